// Round 4
// baseline (247.242 us; speedup 1.0000x reference)
//
#include <hip/hip_runtime.h>

// Problem constants:
//   x: (1, 3, 128, 128) fp32
//   w,q: (3, 124, 124, 25, 5, 5) fp32
//   out: (1, 3, 124, 124, 25) fp32
// out[o] = log( prod_{k=0..24} (1.1 + atan(10*(x_k*w_k - q_k))/pi) )
//
// R4: wave-private async LDS staging.
//  - R1/R2 failed: coalesced staging but MLP-starved + vmcnt(0)+barrier drain.
//  - R3 failed: deep MLP but 100B-stride lane loads -> ~100 cache lines per
//    wave VMEM instr -> TA serialization + L2 thrash (FETCH +32MB).
//  - Here: each wave stages its own 64 outputs' w/q (6400 B each) via 14
//    async global_load_lds issues (16 B/lane, lane-contiguous, one line-touch
//    per byte), waits one vmcnt(0), NO __syncthreads. Waves free-run.

#define IMG   128
#define OUT   124
#define NUM   25
#define NOUT  (3 * OUT * OUT * NUM)            // 1,153,200
#define WTOT  ((long long)NOUT * NUM)          // 28,830,000 floats in w (and q)
#define WPB   4                                // waves per block
#define OPB   (WPB * 64)                       // 256 threads
#define FPW   (64 * NUM)                       // 1600 floats per wave per array

// Minimax atan, |err| ~ 2e-6. Range-reduce with v_rcp_f32.
__device__ __forceinline__ float fast_atan(float z) {
    float az  = __builtin_fabsf(z);
    float r   = __builtin_amdgcn_rcpf(az);
    bool  big = az > 1.0f;
    float t   = big ? r : az;
    float s   = t * t;
    float p   =                     -0.01172120f;
    p = __builtin_fmaf(p, s,         0.05265332f);
    p = __builtin_fmaf(p, s,        -0.11643287f);
    p = __builtin_fmaf(p, s,         0.19354346f);
    p = __builtin_fmaf(p, s,        -0.33262347f);
    p = __builtin_fmaf(p, s,         0.99997726f);
    float a = t * p;
    a = big ? (1.57079632679489662f - a) : a;
    return __builtin_copysignf(a, z);
}

// Async global->LDS, 16 B per lane. LDS dest = wave-uniform base + lane*16.
__device__ __forceinline__ void gl_lds16(const float* g, float* l) {
    __builtin_amdgcn_global_load_lds(
        (const __attribute__((address_space(1))) unsigned int*)g,
        (__attribute__((address_space(3))) unsigned int*)l, 16, 0, 0);
}
__device__ __forceinline__ void gl_lds4(const float* g, float* l) {
    __builtin_amdgcn_global_load_lds(
        (const __attribute__((address_space(1))) unsigned int*)g,
        (__attribute__((address_space(3))) unsigned int*)l, 4, 0, 0);
}

__global__ __launch_bounds__(OPB) void dendrite_kernel(
    const float* __restrict__ x,
    const float* __restrict__ w,
    const float* __restrict__ q,
    float* __restrict__ out)
{
    __shared__ float lw[WPB][FPW];   // 25,600 B
    __shared__ float lq[WPB][FPW];   // 25,600 B  -> 51,200 B/block, 3 blk/CU

    const int lane = threadIdx.x & 63;
    const int wv   = threadIdx.x >> 6;
    const long long wave_id = (long long)blockIdx.x * WPB + wv;
    const long long wo      = wave_id * 64;        // first output of this wave
    const long long fbase   = wo * NUM;            // float index; 6400B-aligned

    // ---- 14 async, fully-coalesced staging issues; no barrier ----
    // 6400 B per array = 6 x 1024 B (16 B/lane) + 256 B tail (4 B/lane).
    #pragma unroll
    for (int it = 0; it < 6; ++it) {
        long long gi = fbase + it * 256 + lane * 4;
        if (gi > WTOT - 4) gi = WTOT - 4;          // clamp OOB lanes (last wave)
        gl_lds16(w + gi, &lw[wv][it * 256 + lane * 4]);
    }
    {
        long long gi = fbase + 1536 + lane;
        if (gi > WTOT - 1) gi = WTOT - 1;
        gl_lds4(w + gi, &lw[wv][1536 + lane]);
    }
    #pragma unroll
    for (int it = 0; it < 6; ++it) {
        long long gi = fbase + it * 256 + lane * 4;
        if (gi > WTOT - 4) gi = WTOT - 4;
        gl_lds16(q + gi, &lq[wv][it * 256 + lane * 4]);
    }
    {
        long long gi = fbase + 1536 + lane;
        if (gi > WTOT - 1) gi = WTOT - 1;
        gl_lds4(q + gi, &lq[wv][1536 + lane]);
    }

    // ---- x patch loads (register, L1 broadcast-heavy) issued before the wait
    const long long o = wo + lane;
    const bool live = (o < NOUT);
    int rem = live ? (int)(o / NUM) : 0;           // (c*OUT + i)*OUT + j
    const int j = rem % OUT;  rem /= OUT;
    const int i = rem % OUT;
    const int c = rem / OUT;
    const float* xp = x + ((long long)c * IMG + i) * IMG + j;

    float xv[NUM];
    #pragma unroll
    for (int u = 0; u < 5; ++u) {
        float4 a;
        __builtin_memcpy(&a, xp + u * IMG, sizeof(float4));
        xv[5*u+0] = a.x; xv[5*u+1] = a.y; xv[5*u+2] = a.z; xv[5*u+3] = a.w;
        xv[5*u+4] = xp[u * IMG + 4];
    }

    // ---- Single drain of all async copies; LDS region is wave-private ----
    asm volatile("s_waitcnt vmcnt(0)" ::: "memory");

    if (!live) return;

    const float* wp = &lw[wv][lane * NUM];   // stride 25 (odd): 2 lanes/bank, free
    const float* qp = &lq[wv][lane * NUM];

    float prod0 = 1.0f, prod1 = 1.0f;
    #pragma unroll
    for (int k = 0; k < NUM; ++k) {
        const float z = 10.0f * __builtin_fmaf(xv[k], wp[k], -qp[k]);
        const float a = fast_atan(z);
        const float term = __builtin_fmaf(a, 0.31830988618379067f, 1.1f);
        if (k & 1) prod1 *= term; else prod0 *= term;
    }
    out[o] = __logf(prod0 * prod1);
}

extern "C" void kernel_launch(void* const* d_in, const int* in_sizes, int n_in,
                              void* d_out, int out_size, void* d_ws, size_t ws_size,
                              hipStream_t stream) {
    const float* x = (const float*)d_in[0];
    const float* w = (const float*)d_in[1];
    const float* q = (const float*)d_in[2];
    float* out = (float*)d_out;

    const int grid = (NOUT + OPB - 1) / OPB;   // 4505 blocks
    dendrite_kernel<<<grid, OPB, 0, stream>>>(x, w, q, out);
}